// Round 22
// baseline (144.650 us; speedup 1.0000x reference)
//
#include <hip/hip_runtime.h>
#include <math.h>

// RecurNN: B=256, L=256, E=100, T=255.
// x_t = W1L*left_t + W1R*right_t + b1; h_t = tanh(x_t); out = sigmoid(W2 h_254 + b2).
// These inputs: right_t always a leaf; left_t = node t-1 (leaf only at t=0).
//
// R22 = R19 (131us) with the CONSUMER rebuilt around uniform quads + pk_fma:
//  - hist layout [Tc][112] "gappy": wave q's k-slice at float offset 28q
//    (16B aligned). Wave q reads ONLY its own slice of hist[n] -> for
//    n = tc-1 the data was written by its own lanes (same-wave DS ordering,
//    no barrier); n < tc-1 is >=1 barrier old. Fast + deep-internal UNIFY.
//  - 6 uniform ds_read_b128 + 1 b32 replace 25 v_readlane (VALU -> DS pipe,
//    which R19 left underloaded), and 24 v_pk_fma_f32 (op_sel broadcast,
//    R4-proven) + 2 fma replace 50 fma. Consumer VALU ~95 -> ~45 instr.
//  - Producer = R19 verbatim (register-RL, DS-light). R21 showed the pk
//    producer's 13 ds_read_b64/wave overloads the shared DS pipe.
// One "lgkmcnt(0); s_barrier" per tick; setprio(1) on consumer critical path.

#define Bc 256
#define Lc 256
#define Ec 100
#define Tc 255
#define W1cols 200
#define HS 112   // hist row stride (floats); slice q at 28q -> byte 112q (16B ok)

#define RL(v, k) __int_as_float(__builtin_amdgcn_readlane(__float_as_int(v), (k)))
#define RF(x)    __builtin_amdgcn_readfirstlane(x)

#define REP25(X) X(0) X(1) X(2) X(3) X(4) X(5) X(6) X(7) X(8) X(9) X(10) X(11) X(12) \
                 X(13) X(14) X(15) X(16) X(17) X(18) X(19) X(20) X(21) X(22) X(23) X(24)

// ---- producer: 25 scalar weight pairs + RL CMALL (R19 verbatim) ----
#define DECLWP(j) float wA##j, wB##j;
#define LOADWP(j) { wA##j = prowA[j]; wB##j = prowB[j]; }
#define CM2(a,b) { const float ra_ = RL(sv,(a)), rb_ = RL(sv,(b)); \
    accA0 = fmaf(ra_, wA##a, accA0); accB0 = fmaf(ra_, wB##a, accB0); \
    accA1 = fmaf(rb_, wA##b, accA1); accB1 = fmaf(rb_, wB##b, accB1); }
#define CM1(a) { const float ra_ = RL(sv,(a)); \
    accA0 = fmaf(ra_, wA##a, accA0); accB0 = fmaf(ra_, wB##a, accB0); }
#define CMALL CM2(0,1) CM2(2,3) CM2(4,5) CM2(6,7) CM2(8,9) CM2(10,11) CM2(12,13) \
              CM2(14,15) CM2(16,17) CM2(18,19) CM2(20,21) CM2(22,23) CM1(24)

// ---- consumer: 25 named float2 weight pairs (Wc_j = {W1L[lc][k], W1L[lc+50][k]}) ----
#define DECLWC(j) float2 Wc##j;
#define LOADWC(j) { Wc##j = make_float2(crowA[j], crowB[j]); }
// pk_fma with h broadcast from lo/hi half (R4-proven op_sel patterns)
#define PKLO(A,W,H) asm("v_pk_fma_f32 %0, %1, %2, %0 op_sel:[0,0,0] op_sel_hi:[1,0,1]" \
                        : "+v"(A) : "v"(W), "v"(H));
#define PKHI(A,W,H) asm("v_pk_fma_f32 %0, %1, %2, %0 op_sel:[0,1,0] op_sel_hi:[1,1,1]" \
                        : "+v"(A) : "v"(W), "v"(H));
// one uniform quad (4 h values) -> 4 pk_fma over weight pairs a..d
#define CQUAD(qq, a,b,c,d) { \
    const float4 h4_ = *(const float4*)(hb + 4*(qq)); \
    const float2 hlo_ = make_float2(h4_.x, h4_.y); \
    const float2 hhi_ = make_float2(h4_.z, h4_.w); \
    PKLO(ac0, Wc##a, hlo_) PKHI(ac1, Wc##b, hlo_) \
    PKLO(ac2, Wc##c, hhi_) PKHI(ac3, Wc##d, hhi_) }
// leaf fallback (t==0): uniform global scalars, component fma
#define LEAF(j) { const float hj_ = g[j]; \
    accA = fmaf(Wc##j.x, hj_, accA); accB = fmaf(Wc##j.y, hj_, accB); }

// generic right-internal fallback: gappy hist row x global W1R row (never hot)
__device__ __noinline__ float slow_dot_g(const float* hg, const float* wr) {
    float a0 = 0.f;
    for (int qq = 0; qq < 4; ++qq)
        for (int j = 0; j < 25; ++j)
            a0 = fmaf(hg[28 * qq + j], wr[25 * qq + j], a0);
    return a0;
}

__global__ __launch_bounds__(512, 2)
void fused(const int* __restrict__ token_ids,
           const int* __restrict__ comp_left,
           const int* __restrict__ comp_right,
           const float* __restrict__ emb,
           const float* __restrict__ W1,
           const float* __restrict__ b1,
           const float* __restrict__ W2,
           const float* __restrict__ b2,
           float* __restrict__ out)
{
    const int b    = blockIdx.x;
    const int tid  = threadIdx.x;          // 0..511
    const int wv   = tid >> 6;             // 0..3 consumers; 4..7 producers
    const int l    = tid & 63;
    const bool cons = (wv < 4);
    const int q    = wv & 3;               // consumer k-slice / producer k-quarter
    const int lc   = (l < 50) ? l : 49;

    __shared__ __align__(16) float hist[Tc * HS];    // 114240 B, gappy rows
    __shared__ float part[2][4][Ec];                 // cons partials, stride-1
    __shared__ float cpart[8][4][Ec];                // c partials, stride-1
    __shared__ int2  ccS[Tc];
    __shared__ int   tokRS[Tc], tokLS[Tc];
    __shared__ float red[4];

    // ---- staging ----
    for (int i = tid; i < Tc; i += 512) {
        const int cl = comp_left [b * Tc + i];
        const int cr = comp_right[b * Tc + i];
        ccS[i]   = make_int2(cl, cr);
        tokRS[i] = (cr < Lc) ? token_ids[b * Lc + cr] : -1;
        tokLS[i] = (cl < Lc) ? token_ids[b * Lc + cl] : -1;
    }

    // ---- weights ----
    const float* crowA = W1 + (size_t)lc * W1cols + 25 * q;          // W1L row lc
    const float* crowB = W1 + (size_t)(lc + 50) * W1cols + 25 * q;   // W1L row lc+50
    REP25(DECLWC)
    const float* prowA = W1 + (size_t)lc * W1cols + Ec + 25 * q;     // W1R row lc
    const float* prowB = W1 + (size_t)(lc + 50) * W1cols + Ec + 25 * q;
    REP25(DECLWP)
    if (cons) { REP25(LOADWC) }
    else      { REP25(LOADWP) }
    const float b1eA = (!cons && q == 0) ? b1[lc] : 0.f;
    const float b1eB = (!cons && q == 0) ? b1[lc + 50] : 0.f;

    __syncthreads();   // staging + weights visible

    // ---- state ----
    float vh = 0.f;                        // consumer lane j<25: h[25q+j]
    int2  cc = make_int2(0, 0);
    float vA0 = 0.f, vA1 = 0.f;            // producer emb-quarter ping-pong
    int   tk0 = -1, tk1 = -1;

    if (cons) {
        cc = ccS[0];
    } else {
        // ---- producer prologue: c[0], c[1] directly; issue loads for t=2,3 ----
        for (int t = 0; t < 2; ++t) {
            const int tk = RF(tokRS[t]);
            float sv = 0.f;
            if (tk >= 0 && l < 25) sv = emb[(size_t)tk * Ec + 25 * q + l];
            float accA0 = b1eA, accA1 = 0.f, accB0 = b1eB, accB1 = 0.f;
            if (tk >= 0) { CMALL }
            if (l < 50) {
                cpart[t][q][lc]      = accA0 + accA1;
                cpart[t][q][lc + 50] = accB0 + accB1;
            }
        }
        tk0 = (2 < Tc) ? RF(tokRS[2]) : -1;
        if (tk0 >= 0 && l < 25) vA0 = emb[(size_t)tk0 * Ec + 25 * q + l];
        tk1 = (3 < Tc) ? RF(tokRS[3]) : -1;
        if (tk1 >= 0 && l < 25) vA1 = emb[(size_t)tk1 * Ec + 25 * q + l];
    }

#define BARRIER asm volatile("s_waitcnt lgkmcnt(0)\n\ts_barrier" ::: "memory");

// one tick: I runtime index, PPc compile-time cons ping-pong, PAR = I&1
#define TICK(I, PPc, PAR)                                                     \
{                                                                             \
    const int i_ = (I);                                                       \
    if (cons) {                                                               \
        const int tc = i_ - 1;                                                \
        if (tc >= 0) {                                                        \
            __builtin_amdgcn_s_setprio(1);                                    \
            const int li = RF(cc.x);                                          \
            const int ri = RF(cc.y);                                          \
            /* cpart[tc] written >=2 barriers ago: read early, hides under    \
               the pk stream. */                                              \
            float cp0 = 0.f, cp1 = 0.f, cp2 = 0.f, cp3 = 0.f;                 \
            if (l < 25) {                                                     \
                const int r_ = 25 * q + l;                                    \
                cp0 = cpart[tc & 7][0][r_]; cp1 = cpart[tc & 7][1][r_];       \
                cp2 = cpart[tc & 7][2][r_]; cp3 = cpart[tc & 7][3][r_];       \
            }                                                                 \
            float accA = 0.f, accB = 0.f;                                     \
            if (li >= Lc) {                                                   \
                const int n = li - Lc;                                        \
                if (n < tc) {          /* covers n==tc-1 (own-wave write) */  \
                    const float* hb = &hist[n * HS + 28 * q];                 \
                    float2 ac0 = make_float2(0.f, 0.f), ac1 = ac0;            \
                    float2 ac2 = ac0, ac3 = ac0;                              \
                    CQUAD(0, 0,1,2,3)   CQUAD(1, 4,5,6,7)                     \
                    CQUAD(2, 8,9,10,11) CQUAD(3, 12,13,14,15)                 \
                    CQUAD(4, 16,17,18,19) CQUAD(5, 20,21,22,23)               \
                    const float h24_ = hb[24];                                \
                    accA = fmaf(Wc24.x, h24_,                                 \
                                (ac0.x + ac1.x) + (ac2.x + ac3.x));           \
                    accB = fmaf(Wc24.y, h24_,                                 \
                                (ac0.y + ac1.y) + (ac2.y + ac3.y));           \
                }                       /* n >= tc: zeros, per reference */   \
            } else {                    /* left leaf (t==0 for these inputs) */\
                const int tl = RF(tokLS[tc]);                                 \
                if (tl >= 0) {                                                \
                    const float* g = emb + (size_t)tl * Ec + 25 * q;          \
                    REP25(LEAF)                                               \
                }                                                             \
            }                                                                 \
            if (l < 50) {                                                     \
                part[PPc][q][lc]      = accA;                                 \
                part[PPc][q][lc + 50] = accB;                                 \
            }                                                                 \
            BARRIER                                                           \
            if (l < 25) {                                                     \
                const int r = 25 * q + l;                                     \
                float x = ((part[PPc][0][r] + part[PPc][1][r]) +              \
                           (part[PPc][2][r] + part[PPc][3][r])) +             \
                          ((cp0 + cp1) + (cp2 + cp3));                        \
                if (ri >= Lc) {         /* generic right-internal (cold) */   \
                    const int n2 = ri - Lc;                                   \
                    if (n2 < tc) x += slow_dot_g(&hist[n2 * HS],              \
                                                 W1 + (size_t)r * W1cols + Ec);\
                }                                                             \
                const float u = __expf(2.f * x);                              \
                vh = 1.f - 2.f / (u + 1.f);    /* tanh, exact identity */     \
                hist[tc * HS + 28 * q + l] = vh;                              \
            }                                                                 \
            __builtin_amdgcn_s_setprio(0);                                    \
            if (tc + 1 < Tc) cc = ccS[tc + 1];                                \
        } else {                                                              \
            BARRIER                                                           \
        }                                                                     \
    } else {                                                                  \
        const int t = i_ + 2;                                                 \
        if (t < Tc) {                                                         \
            const float sv  = (PAR) ? vA1 : vA0;   /* loaded 2 ticks ago */   \
            const int   tkc = (PAR) ? tk1 : tk0;                              \
            const int   tn  = t + 2;               /* refill this slot */     \
            const int tknew = (tn < Tc) ? RF(tokRS[tn]) : -1;                 \
            float nv = 0.f;                                                   \
            if (tknew >= 0 && l < 25) nv = emb[(size_t)tknew * Ec + 25 * q + l];\
            if (PAR) { vA1 = nv; tk1 = tknew; } else { vA0 = nv; tk0 = tknew; }\
            float accA0 = b1eA, accA1 = 0.f, accB0 = b1eB, accB1 = 0.f;       \
            if (tkc >= 0) { CMALL }                                           \
            if (l < 50) {                                                     \
                cpart[t & 7][q][lc]      = accA0 + accA1;                     \
                cpart[t & 7][q][lc + 50] = accB0 + accB1;                     \
            }                                                                 \
        }                                                                     \
        BARRIER                                                               \
    }                                                                         \
}

    // ---- main loop: 256 ticks, unroll-2 ----
    #pragma unroll 1
    for (int i2 = 0; i2 < 256; i2 += 2) {
        TICK(i2,     1, 0)
        TICK(i2 + 1, 0, 1)
    }
#undef TICK
#undef BARRIER

    // ---- out[b] = sigmoid(W2 . h_254 + b2) ----
    if (cons) {
        float pv = 0.f;
        if (l < 25) pv = W2[25 * q + l] * vh;
        #pragma unroll
        for (int off = 32; off > 0; off >>= 1) pv += __shfl_down(pv, off, 64);
        if (l == 0) red[q] = pv;
    }
    __syncthreads();
    if (tid == 0)
        out[b] = 1.f / (1.f + __expf(-((red[0] + red[1]) + (red[2] + red[3]) + b2[0])));
}

extern "C" void kernel_launch(void* const* d_in, const int* in_sizes, int n_in,
                              void* d_out, int out_size, void* d_ws, size_t ws_size,
                              hipStream_t stream) {
    const int*   token_ids  = (const int*)  d_in[0];
    const int*   comp_left  = (const int*)  d_in[1];
    const int*   comp_right = (const int*)  d_in[2];
    const float* emb        = (const float*)d_in[3];
    const float* W1         = (const float*)d_in[4];
    const float* b1         = (const float*)d_in[5];
    const float* W2         = (const float*)d_in[6];
    const float* b2         = (const float*)d_in[7];
    float*       out        = (float*)d_out;

    fused<<<Bc, 512, 0, stream>>>(token_ids, comp_left, comp_right,
                                  emb, W1, b1, W2, b2, out);
}